// Round 7
// baseline (290.859 us; speedup 1.0000x reference)
//
#include <hip/hip_runtime.h>
#include <math.h>

#define HH 64
// Bucket = col >> 8 (256 nodes per bucket). Requires N <= 65536 (N=50000 here),
// also required by the 16-bit row packing in pairbuf, and NB <= 256.
#define BSH 8
#define BSZ 256
#define HBLK 256                       // blocks participating in histogram/scatter
#define HSTRIDE (HBLK * 256)           // edge-slice stride (must match in both passes)

typedef _Float16 half_t;
typedef _Float16 half4_t __attribute__((ext_vector_type(4)));

// ---------------- layer-1 GEMM (fp32 x @ W1 -> fp16) + bucket histogram -------
// Blocks 0..HBLK-1 additionally compute a per-block bucket histogram of col[]
// into ph[bid][bucket] (pure overwrite -> no zero-init kernel, no global atomics).
__global__ __launch_bounds__(256, 3)
void k_gemm1_hist(const float* __restrict__ x, const float* __restrict__ W,
                  half_t* __restrict__ out, int n,
                  const int* __restrict__ col, int E, int* __restrict__ ph) {
    constexpr int FIN = 128;
    constexpr int KC = 32;
    __shared__ __align__(16) float Ws[FIN][HH];
    __shared__ __align__(16) float xs_t[KC][68];
    __shared__ int hh[BSZ];
    const int tid = threadIdx.x;
    const int bid = blockIdx.x;

    // ---- histogram slice (blocks 0..HBLK-1) ----
    if (bid < HBLK) {
        hh[tid] = 0;
        __syncthreads();
        for (int e = bid * 256 + tid; e < E; e += HSTRIDE)
            atomicAdd(&hh[col[e] >> BSH], 1);
        __syncthreads();
        ph[bid * BSZ + tid] = hh[tid];
    }

    // ---- GEMM tile (verified round-4 structure) ----
    const int tx = tid & 15;
    const int ty = tid >> 4;
    const int node0 = bid * 64;
    if (node0 >= n) return;

    for (int i = tid * 4; i < FIN * HH; i += 1024)
        *(float4*)&Ws[0][i] = *(const float4*)&W[i];

    float acc[4][4] = {};
    const int rr0 = tid >> 3;
    const int cc  = (tid & 7) * 4;

    for (int kc = 0; kc < FIN; kc += KC) {
        __syncthreads();
        for (int rr = rr0; rr < 64; rr += 32) {
            float4 v = make_float4(0.f, 0.f, 0.f, 0.f);
            if (node0 + rr < n) v = *(const float4*)&x[(size_t)(node0 + rr) * FIN + kc + cc];
            xs_t[cc + 0][rr] = v.x;
            xs_t[cc + 1][rr] = v.y;
            xs_t[cc + 2][rr] = v.z;
            xs_t[cc + 3][rr] = v.w;
        }
        __syncthreads();
#pragma unroll 4
        for (int k = 0; k < KC; ++k) {
            float4 a4 = *(const float4*)&xs_t[k][ty * 4];
            float4 b4 = *(const float4*)&Ws[kc + k][tx * 4];
            acc[0][0] = fmaf(a4.x, b4.x, acc[0][0]);
            acc[0][1] = fmaf(a4.x, b4.y, acc[0][1]);
            acc[0][2] = fmaf(a4.x, b4.z, acc[0][2]);
            acc[0][3] = fmaf(a4.x, b4.w, acc[0][3]);
            acc[1][0] = fmaf(a4.y, b4.x, acc[1][0]);
            acc[1][1] = fmaf(a4.y, b4.y, acc[1][1]);
            acc[1][2] = fmaf(a4.y, b4.z, acc[1][2]);
            acc[1][3] = fmaf(a4.y, b4.w, acc[1][3]);
            acc[2][0] = fmaf(a4.z, b4.x, acc[2][0]);
            acc[2][1] = fmaf(a4.z, b4.y, acc[2][1]);
            acc[2][2] = fmaf(a4.z, b4.z, acc[2][2]);
            acc[2][3] = fmaf(a4.z, b4.w, acc[2][3]);
            acc[3][0] = fmaf(a4.w, b4.x, acc[3][0]);
            acc[3][1] = fmaf(a4.w, b4.y, acc[3][1]);
            acc[3][2] = fmaf(a4.w, b4.z, acc[3][2]);
            acc[3][3] = fmaf(a4.w, b4.w, acc[3][3]);
        }
    }
#pragma unroll
    for (int i = 0; i < 4; ++i) {
        int node = node0 + ty * 4 + i;
        if (node < n) {
            half4_t o = {(half_t)acc[i][0], (half_t)acc[i][1],
                         (half_t)acc[i][2], (half_t)acc[i][3]};
            *(half4_t*)(out + (size_t)node * HH + tx * 4) = o;
        }
    }
}

// ---------------- scatter: atomic-free via ph-prefix; folds in the bucket scan ----
__global__ __launch_bounds__(256) void k_bscatter2(const int* __restrict__ row,
                                                   const int* __restrict__ col, int E,
                                                   const int* __restrict__ ph,
                                                   int* __restrict__ base,
                                                   int* __restrict__ pair, int nb) {
    __shared__ int cur[BSZ];
    __shared__ int ssc[BSZ];
    const int b = blockIdx.x;
    const int t = threadIdx.x;
    int before = 0, total = 0;
    for (int k = 0; k < HBLK; ++k) {
        int v = ph[k * BSZ + t];
        total += v;
        if (k < b) before += v;
    }
    ssc[t] = total;
    __syncthreads();
    for (int d = 1; d < 256; d <<= 1) {
        int x2 = ssc[t];
        if (t >= d) x2 += ssc[t - d];
        __syncthreads();
        ssc[t] = x2;
        __syncthreads();
    }
    int excl = ssc[t] - total;
    cur[t] = excl + before;
    if (b == 0) {
        if (t < nb) base[t] = excl;
        if (t == 0) base[nb] = E;      // all edges land in buckets < nb
    }
    __syncthreads();
    for (int e = b * 256 + t; e < E; e += HSTRIDE) {
        int c = col[e];
        int pos = atomicAdd(&cur[c >> BSH], 1);   // LDS atomic only
        pair[pos] = (row[e] & 0xFFFF) | ((c & (BSZ - 1)) << 16);
    }
}

// ---------------- per-bucket fine CSR build (unchanged, round-4 verified) -----
__global__ __launch_bounds__(256) void k_bcsr(const int* __restrict__ pair,
                                              const int* __restrict__ base,
                                              int* __restrict__ rowptr,
                                              int* __restrict__ cnt,
                                              float* __restrict__ dinv,
                                              int* __restrict__ csr, int n) {
    __shared__ int lcnt[BSZ];
    __shared__ int ssc[BSZ];
    __shared__ int lcur[BSZ];
    const int b = blockIdx.x;
    const int t = threadIdx.x;
    const int nd0 = b << BSH;
    const int e0 = base[b];
    const int e1 = base[b + 1];

    lcnt[t] = 0;
    __syncthreads();
    for (int e = e0 + t; e < e1; e += 256)
        atomicAdd(&lcnt[(pair[e] >> 16) & (BSZ - 1)], 1);
    __syncthreads();
    int v = lcnt[t];
    ssc[t] = v;
    __syncthreads();
    for (int d = 1; d < 256; d <<= 1) {
        int x2 = ssc[t];
        if (t >= d) x2 += ssc[t - d];
        __syncthreads();
        ssc[t] = x2;
        __syncthreads();
    }
    int excl = ssc[t] - v;
    lcur[t] = e0 + excl;
    int node = nd0 + t;
    if (node < n) {
        rowptr[node] = e0 + excl;
        cnt[node]    = v;
        dinv[node]   = rsqrtf((float)(v + 1));
    }
    __syncthreads();
    for (int e = e0 + t; e < e1; e += 256) {
        int pr = pair[e];
        int pos = atomicAdd(&lcur[(pr >> 16) & (BSZ - 1)], 1);
        csr[pos] = pr & 0xFFFF;
    }
}

// ---------------- dense transform layers 2-3 (fp16 in/out, round-4 verified) ---
template<int FIN>
__global__ __launch_bounds__(256, 4)
void k_gemm(const half_t* __restrict__ xin, const float* __restrict__ W,
            const float* __restrict__ dinv, half_t* __restrict__ out, int n) {
    constexpr int KC = 32;
    __shared__ __align__(16) float Ws[FIN][HH];
    __shared__ __align__(16) float xs_t[KC][68];
    const int tid = threadIdx.x;
    const int tx = tid & 15;
    const int ty = tid >> 4;
    const int node0 = blockIdx.x * 64;
    if (node0 >= n) return;

    for (int i = tid * 4; i < FIN * HH; i += 1024)
        *(float4*)&Ws[0][i] = *(const float4*)&W[i];

    float acc[4][4] = {};
    const int rr0 = tid >> 3;
    const int cc  = (tid & 7) * 4;

    for (int kc = 0; kc < FIN; kc += KC) {
        __syncthreads();
        for (int rr = rr0; rr < 64; rr += 32) {
            float4 v = make_float4(0.f, 0.f, 0.f, 0.f);
            if (node0 + rr < n) {
                half4_t hv = *(const half4_t*)(xin + (size_t)(node0 + rr) * FIN + kc + cc);
                v = make_float4((float)hv.x, (float)hv.y, (float)hv.z, (float)hv.w);
            }
            xs_t[cc + 0][rr] = v.x;
            xs_t[cc + 1][rr] = v.y;
            xs_t[cc + 2][rr] = v.z;
            xs_t[cc + 3][rr] = v.w;
        }
        __syncthreads();
#pragma unroll 4
        for (int k = 0; k < KC; ++k) {
            float4 a4 = *(const float4*)&xs_t[k][ty * 4];
            float4 b4 = *(const float4*)&Ws[kc + k][tx * 4];
            acc[0][0] = fmaf(a4.x, b4.x, acc[0][0]);
            acc[0][1] = fmaf(a4.x, b4.y, acc[0][1]);
            acc[0][2] = fmaf(a4.x, b4.z, acc[0][2]);
            acc[0][3] = fmaf(a4.x, b4.w, acc[0][3]);
            acc[1][0] = fmaf(a4.y, b4.x, acc[1][0]);
            acc[1][1] = fmaf(a4.y, b4.y, acc[1][1]);
            acc[1][2] = fmaf(a4.y, b4.z, acc[1][2]);
            acc[1][3] = fmaf(a4.y, b4.w, acc[1][3]);
            acc[2][0] = fmaf(a4.z, b4.x, acc[2][0]);
            acc[2][1] = fmaf(a4.z, b4.y, acc[2][1]);
            acc[2][2] = fmaf(a4.z, b4.z, acc[2][2]);
            acc[2][3] = fmaf(a4.z, b4.w, acc[2][3]);
            acc[3][0] = fmaf(a4.w, b4.x, acc[3][0]);
            acc[3][1] = fmaf(a4.w, b4.y, acc[3][1]);
            acc[3][2] = fmaf(a4.w, b4.z, acc[3][2]);
            acc[3][3] = fmaf(a4.w, b4.w, acc[3][3]);
        }
    }
#pragma unroll
    for (int i = 0; i < 4; ++i) {
        int node = node0 + ty * 4 + i;
        if (node < n) {
            float d = dinv[node];
            half4_t o = {(half_t)(acc[i][0] * d), (half_t)(acc[i][1] * d),
                         (half_t)(acc[i][2] * d), (half_t)(acc[i][3] * d)};
            *(half4_t*)(out + (size_t)node * HH + tx * 4) = o;
        }
    }
}

// ---------------- gather: quarter-wave, SHFL-FREE inner loop ------------------
// R6 diagnosis: the old inner loop issued 8 ds_bpermute (shfl) per 16 edges with
// row-load addresses dependent on them -> LDS-pipe throughput + serialization
// bound (fp32->fp16 barely moved it). Now each quarter loads its 4 edge indices
// DIRECTLY from csr (16 lanes read the same 4B -> 1 coalesced L2-hot transaction)
// and weights directly from dinv (200KB, L2-resident). Zero inner-loop DS ops;
// only the 12-op epilogue reduce remains. FMA order per lane mirrored exactly
// (a0: edges 0,2; a1: edges 1,3) -> bit-identical numerics to round 4/6.
template<bool WEIGHTED, bool HOUT>
__global__ __launch_bounds__(256) void k_gather_q(const half_t* __restrict__ lin,
                                                  const int* __restrict__ csr,
                                                  const int* __restrict__ rowptr,
                                                  const int* __restrict__ cnt,
                                                  const float* __restrict__ dinv,
                                                  const float* __restrict__ b,
                                                  void* __restrict__ hout, int n) {
    int node = blockIdx.x * 4 + (threadIdx.x >> 6);
    int lane = threadIdx.x & 63;
    if (node >= n) return;
    const int q  = lane >> 4;
    const int fl = (lane & 15) * 4;
    int start = rowptr[node];
    int end = start + cnt[node];
    float di = dinv[node];

    float4 a0 = make_float4(0.f, 0.f, 0.f, 0.f);
    float4 a1 = make_float4(0.f, 0.f, 0.f, 0.f);

    for (int eb = start; eb < end; eb += 16) {
        const int e0i = eb + q * 4;
        const bool g0 = (e0i + 0) < end;
        const bool g1 = (e0i + 1) < end;
        const bool g2 = (e0i + 2) < end;
        const bool g3 = (e0i + 3) < end;
        int s0 = g0 ? csr[e0i + 0] : 0;
        int s1 = g1 ? csr[e0i + 1] : 0;
        int s2 = g2 ? csr[e0i + 2] : 0;
        int s3 = g3 ? csr[e0i + 3] : 0;
        float w0, w1, w2, w3;
        if (WEIGHTED) {
            w0 = g0 ? dinv[s0] : 0.f;
            w1 = g1 ? dinv[s1] : 0.f;
            w2 = g2 ? dinv[s2] : 0.f;
            w3 = g3 ? dinv[s3] : 0.f;
        } else {
            w0 = g0 ? 1.f : 0.f;
            w1 = g1 ? 1.f : 0.f;
            w2 = g2 ? 1.f : 0.f;
            w3 = g3 ? 1.f : 0.f;
        }
        half4_t v0 = *(const half4_t*)&lin[(size_t)s0 * HH + fl];
        half4_t v1 = *(const half4_t*)&lin[(size_t)s1 * HH + fl];
        half4_t v2 = *(const half4_t*)&lin[(size_t)s2 * HH + fl];
        half4_t v3 = *(const half4_t*)&lin[(size_t)s3 * HH + fl];
        a0.x = fmaf(w0, (float)v0.x, a0.x); a0.y = fmaf(w0, (float)v0.y, a0.y);
        a0.z = fmaf(w0, (float)v0.z, a0.z); a0.w = fmaf(w0, (float)v0.w, a0.w);
        a1.x = fmaf(w1, (float)v1.x, a1.x); a1.y = fmaf(w1, (float)v1.y, a1.y);
        a1.z = fmaf(w1, (float)v1.z, a1.z); a1.w = fmaf(w1, (float)v1.w, a1.w);
        a0.x = fmaf(w2, (float)v2.x, a0.x); a0.y = fmaf(w2, (float)v2.y, a0.y);
        a0.z = fmaf(w2, (float)v2.z, a0.z); a0.w = fmaf(w2, (float)v2.w, a0.w);
        a1.x = fmaf(w3, (float)v3.x, a1.x); a1.y = fmaf(w3, (float)v3.y, a1.y);
        a1.z = fmaf(w3, (float)v3.z, a1.z); a1.w = fmaf(w3, (float)v3.w, a1.w);
    }
    float4 acc = make_float4(a0.x + a1.x, a0.y + a1.y, a0.z + a1.z, a0.w + a1.w);
#pragma unroll
    for (int off = 16; off < 64; off <<= 1) {
        acc.x += __shfl_xor(acc.x, off, 64);
        acc.y += __shfl_xor(acc.y, off, 64);
        acc.z += __shfl_xor(acc.z, off, 64);
        acc.w += __shfl_xor(acc.w, off, 64);
    }
    half4_t self = *(const half4_t*)&lin[(size_t)node * HH + fl];
    float sw = WEIGHTED ? di : 1.f;
    acc.x = fmaf(sw, (float)self.x, acc.x);
    acc.y = fmaf(sw, (float)self.y, acc.y);
    acc.z = fmaf(sw, (float)self.z, acc.z);
    acc.w = fmaf(sw, (float)self.w, acc.w);
    float4 b4 = *(const float4*)&b[fl];
    float4 v4 = make_float4(fmaf(di, acc.x, b4.x), fmaf(di, acc.y, b4.y),
                            fmaf(di, acc.z, b4.z), fmaf(di, acc.w, b4.w));
    float ss = v4.x * v4.x + v4.y * v4.y + v4.z * v4.z + v4.w * v4.w;
#pragma unroll
    for (int off = 1; off < 16; off <<= 1) ss += __shfl_xor(ss, off, 64);
    float inv = 1.f / fmaxf(sqrtf(ss), 1e-12f);
    v4.x = fmaxf(v4.x * inv, 0.f);
    v4.y = fmaxf(v4.y * inv, 0.f);
    v4.z = fmaxf(v4.z * inv, 0.f);
    v4.w = fmaxf(v4.w * inv, 0.f);
    if (q == 0) {
        if constexpr (HOUT) {
            half4_t o = {(half_t)v4.x, (half_t)v4.y, (half_t)v4.z, (half_t)v4.w};
            *(half4_t*)((half_t*)hout + (size_t)node * HH + fl) = o;
        } else {
            *(float4*)((float*)hout + (size_t)node * HH + fl) = v4;
        }
    }
}

// ---------------- fused pool + classifier: one block per graph, no atomics ----
__global__ __launch_bounds__(256) void k_poolfinal(const float* __restrict__ node_emb,
                                                   const int* __restrict__ batch,
                                                   const float* __restrict__ Wm,
                                                   const float* __restrict__ bm,
                                                   float* __restrict__ logits,
                                                   float* __restrict__ probs,
                                                   float* __restrict__ graph_emb, int n) {
    __shared__ float part[4][HH];
    __shared__ float semb[HH];
    __shared__ float slog[16];
    const int g = blockIdx.x;
    const int tid = threadIdx.x;
    const int lane = tid & 63, w = tid >> 6;

    int lo = 0, hi = n;
    while (lo < hi) { int mid = (lo + hi) >> 1; if (batch[mid] < g) lo = mid + 1; else hi = mid; }
    const int s = lo;
    hi = n;
    while (lo < hi) { int mid = (lo + hi) >> 1; if (batch[mid] < g + 1) lo = mid + 1; else hi = mid; }
    const int e2 = lo;

    float acc = 0.f;
    for (int i = s + w; i < e2; i += 4) acc += node_emb[(size_t)i * HH + lane];
    part[w][lane] = acc;
    __syncthreads();
    if (tid < HH) {
        float m = part[0][tid] + part[1][tid] + part[2][tid] + part[3][tid];
        m /= fmaxf((float)(e2 - s), 1.f);
        graph_emb[(size_t)g * HH + tid] = m;
        semb[tid] = m;
    }
    __syncthreads();
    if (tid < 10) {
        float a2 = bm[tid];
        for (int k = 0; k < HH; ++k) a2 = fmaf(semb[k], Wm[k * 10 + tid], a2);
        slog[tid] = a2;
    }
    __syncthreads();
    if (tid < 10) {
        float mx = -1e30f;
        for (int j = 0; j < 10; ++j) mx = fmaxf(mx, slog[j]);
        float den = 0.f;
        for (int j = 0; j < 10; ++j) den += __expf(slog[j] - mx);
        float lg = slog[tid];
        logits[g * 10 + tid] = lg;
        probs[g * 10 + tid] = __expf(lg - mx) / den;
    }
}

// ---------------- launch ----------------

extern "C" void kernel_launch(void* const* d_in, const int* in_sizes, int n_in,
                              void* d_out, int out_size, void* d_ws, size_t ws_size,
                              hipStream_t stream) {
    const float* x     = (const float*)d_in[0];
    const int*   ei    = (const int*)  d_in[1];
    const int*   batch = (const int*)  d_in[2];
    const float* W1 = (const float*)d_in[3];  const float* b1 = (const float*)d_in[4];
    const float* W2 = (const float*)d_in[5];  const float* b2 = (const float*)d_in[6];
    const float* W3 = (const float*)d_in[7];  const float* b3 = (const float*)d_in[8];
    const float* Wm = (const float*)d_in[9];  const float* bm = (const float*)d_in[10];

    const int N = in_sizes[2];
    const int E = in_sizes[1] / 2;
    const int G = (out_size - N * HH) / (2 * 10 + HH);
    const int NB = (N + BSZ - 1) >> BSH;

    const int* row = ei;
    const int* col = ei + E;

    float* out       = (float*)d_out;
    float* logits    = out;
    float* probs     = out + (size_t)G * 10;
    float* node_emb  = out + (size_t)2 * G * 10;
    float* graph_emb = node_emb + (size_t)N * HH;

    char* w = (char*)d_ws;
    auto alloc = [&](size_t bytes) { char* p = w; w += (bytes + 255) & ~(size_t)255; return p; };
    float* dinv    = (float*)alloc((size_t)N * 4);
    int*   cnt     = (int*)  alloc((size_t)N * 4);
    int*   rowptr  = (int*)  alloc((size_t)N * 4);
    int*   ph      = (int*)  alloc((size_t)HBLK * BSZ * 4);
    int*   base    = (int*)  alloc((size_t)(NB + 1) * 4);
    int*   pairbuf = (int*)  alloc((size_t)E * 4);
    int*   csr     = (int*)  alloc((size_t)E * 4);
    half_t* bufA   = (half_t*)alloc((size_t)N * HH * 2);
    half_t* bufB   = (half_t*)alloc((size_t)N * HH * 2);

    const int B = 256;
    dim3 blk(B);
    int node_blocks = (N + 3) / 4;
    int gemm_blocks = (N + 63) / 64;
    int g1_blocks = gemm_blocks > HBLK ? gemm_blocks : HBLK;

    k_gemm1_hist<<<g1_blocks, blk, 0, stream>>>(x, W1, bufA, N, col, E, ph);
    k_bscatter2<<<HBLK, blk, 0, stream>>>(row, col, E, ph, base, pairbuf, NB);
    k_bcsr<<<NB, blk, 0, stream>>>(pairbuf, base, rowptr, cnt, dinv, csr, N);

    k_gather_q<true, true><<<node_blocks, blk, 0, stream>>>(bufA, csr, rowptr, cnt, dinv, b1, bufB, N);
    k_gemm<64><<<gemm_blocks, blk, 0, stream>>>(bufB, W2, dinv, bufA, N);
    k_gather_q<false, true><<<node_blocks, blk, 0, stream>>>(bufA, csr, rowptr, cnt, dinv, b2, bufB, N);
    k_gemm<64><<<gemm_blocks, blk, 0, stream>>>(bufB, W3, dinv, bufA, N);
    k_gather_q<false, false><<<node_blocks, blk, 0, stream>>>(bufA, csr, rowptr, cnt, dinv, b3, node_emb, N);

    k_poolfinal<<<G, blk, 0, stream>>>(node_emb, batch, Wm, bm, logits, probs, graph_emb, N);
}